// Round 3
// baseline (129.317 us; speedup 1.0000x reference)
//
#include <hip/hip_runtime.h>

// HMLoss: 4-region histogram-matching L1 loss, H=W=2048.
// One image pass builds, per (src-region, channel), a 512-entry fine histogram
// keyed by key = 2*trunc(v) + (cdfbin(v) - trunc(v)), with packed (N<<48 | S)
// where S = sum of v in exact 2^23 fixed point. Loss is then computed from
// (N_b, S_b) per coarse bin without re-reading the image:
//   |v - t| summed over bin b = (t<=b) ? S_b - N_b*t : N_b*t - S_b   (exact).
//
// ws layout (4 flush copies to spread global-atomic contention):
//   [0, 98304)        u32 gN[4][6144]   src fine-bin counts
//   [98304, 294912)   u64 gS[4][6144]   src fine-bin sums (2^23 fixed point)
//   [294912, 344064)  u32 gT[4][3072]   tar cdf histograms
//   [344064, 344072)  s64 acc           loss accumulator (2^23 fixed point)

#define FACEA_BITS ((1u<<1)|(1u<<7)|(1u<<8)|(1u<<10)|(1u<<11)|(1u<<14))
#define FACEB_BITS ((1u<<1)|(1u<<7)|(1u<<8)|(1u<<10)|(1u<<14))
#define HAIR_BITS  (1u<<17)
#define EYEL_BITS  ((1u<<2)|(1u<<4))
#define EYER_BITS  ((1u<<3)|(1u<<5))

typedef unsigned long long u64;
typedef long long s64;

__device__ __forceinline__ float denorm255(float x) {
  float t = (x + 1.0f) * 0.5f;
  t = fminf(fmaxf(t, 0.0f), 1.0f);
  return t * 255.0f;
}

__device__ __forceinline__ int bin_of(float v) {
  int b = (int)floorf(v * (256.0f / 255.0f));
  b = b < 0 ? 0 : b;
  return b > 255 ? 255 : b;
}

__device__ __forceinline__ int regionA(unsigned bit) {
  if (bit & FACEA_BITS) return 0;
  if (bit & HAIR_BITS)  return 1;
  if (bit & EYEL_BITS)  return 2;
  if (bit & EYER_BITS)  return 3;
  return -1;
}
__device__ __forceinline__ int regionB(unsigned bit) {
  if (bit & FACEB_BITS) return 0;
  if (bit & HAIR_BITS)  return 1;
  if (bit & EYEL_BITS)  return 2;
  if (bit & EYER_BITS)  return 3;
  return -1;
}

__global__ __launch_bounds__(1024) void hist_kernel(
    const float* __restrict__ fake, const float* __restrict__ refb,
    const int* __restrict__ ma, const int* __restrict__ mb,
    unsigned* __restrict__ gN, u64* __restrict__ gS,
    unsigned* __restrict__ gT, int npix) {
  __shared__ u64 ns[6144];       // [region][chan][512] packed N<<48 | S
  __shared__ unsigned th[3072];  // tar cdf hist [region][chan][256]
  for (int i = threadIdx.x; i < 6144; i += blockDim.x) ns[i] = 0ull;
  for (int i = threadIdx.x; i < 3072; i += blockDim.x) th[i] = 0u;
  __syncthreads();

  const int nq = npix >> 2;
  const int stride = gridDim.x * blockDim.x;
  const float4* f0p = (const float4*)fake;
  const float4* f1p = (const float4*)(fake + npix);
  const float4* f2p = (const float4*)(fake + 2 * npix);
  const float4* r0p = (const float4*)refb;
  const float4* r1p = (const float4*)(refb + npix);
  const float4* r2p = (const float4*)(refb + 2 * npix);
  const int4* map = (const int4*)ma;
  const int4* mbp = (const int4*)mb;

  for (int q = blockIdx.x * blockDim.x + threadIdx.x; q < nq; q += stride) {
    int4 m4 = map[q];
    int4 b4 = mbp[q];
    float4 f0 = f0p[q], f1 = f1p[q], f2 = f2p[q];
    float4 r0 = r0p[q], r1 = r1p[q], r2 = r2p[q];
    int mm[4] = {m4.x, m4.y, m4.z, m4.w};
    int bb[4] = {b4.x, b4.y, b4.z, b4.w};
    float fa[3][4] = {{f0.x,f0.y,f0.z,f0.w},{f1.x,f1.y,f1.z,f1.w},{f2.x,f2.y,f2.z,f2.w}};
    float rr[3][4] = {{r0.x,r0.y,r0.z,r0.w},{r1.x,r1.y,r1.z,r1.w},{r2.x,r2.y,r2.z,r2.w}};
#pragma unroll
    for (int k = 0; k < 4; ++k) {
      int sreg = regionA(1u << (mm[k] & 31));
      if (sreg >= 0) {
#pragma unroll
        for (int c = 0; c < 3; ++c) {
          float v = denorm255(fa[c][k]);
          int c1 = (int)v;                    // trunc == floor, v >= 0
          int c2 = bin_of(v);
          int key = sreg * 1536 + c * 512 + 2 * c1 + (c2 - c1);
          u64 pack = (1ull << 48) | (u64)(v * 8388608.0f);  // exact
          atomicAdd(&ns[key], pack);
        }
      }
      int treg = regionB(1u << (bb[k] & 31));
      int fval = (treg == 0 ? 1 : 0) + ((mm[k] == 11) ? 1 : 0);
      if (fval > 0) {
        float fs = (float)fval;
#pragma unroll
        for (int c = 0; c < 3; ++c)
          atomicAdd(&th[c * 256 + bin_of(denorm255(rr[c][k]) * fs)], 1u);
      }
      if (treg >= 1) {
#pragma unroll
        for (int c = 0; c < 3; ++c)
          atomicAdd(&th[treg * 768 + c * 256 + bin_of(denorm255(rr[c][k]))], 1u);
      }
    }
  }
  __syncthreads();

  // flush to one of 4 global copies, rotated start to spread contention.
  // NOTE: 6144/3072 are NOT powers of two -> conditional wrap, never & mask.
  int copy = blockIdx.x & 3;
  int rot = (blockIdx.x >> 2) & 63;
  for (int i = threadIdx.x; i < 6144; i += blockDim.x) {
    int j = i + rot * 96; if (j >= 6144) j -= 6144;
    u64 v = ns[j];
    if (v) {
      atomicAdd(&gN[copy * 6144 + j], (unsigned)(v >> 48));
      atomicAdd(&gS[copy * 6144 + j], v & 0xFFFFFFFFFFFFull);
    }
  }
  for (int i = threadIdx.x; i < 3072; i += blockDim.x) {
    int j = i + rot * 48; if (j >= 3072) j -= 3072;
    unsigned v = th[j];
    if (v) atomicAdd(&gT[copy * 3072 + j], v);
  }
}

// 12 blocks, one per (region, channel): sum copies, build both CDFs
// (bit-faithful serial f32 cumsum), transfer table, then the exact-integer
// loss contribution per coarse bin. Block-reduce -> atomic s64.
__global__ __launch_bounds__(256) void cdf_loss_kernel(
    const unsigned* __restrict__ gN, const u64* __restrict__ gS,
    const unsigned* __restrict__ gT, u64* __restrict__ acc) {
  __shared__ unsigned Nf[512];
  __shared__ u64 Sf[512];
  __shared__ float dcdf[256];
  __shared__ float acdf[256];
  __shared__ s64 red[256];
  int rc = blockIdx.x;             // 0..11
  int base = (rc / 3) * 1536 + (rc % 3) * 512;
  int t = threadIdx.x;

  // sum the 4 flush copies
  for (int e = 0; e < 2; ++e) {
    int key = 2 * t + e;
    unsigned n = 0; u64 s = 0;
#pragma unroll
    for (int cp = 0; cp < 4; ++cp) {
      n += gN[cp * 6144 + base + key];
      s += gS[cp * 6144 + base + key];
    }
    Nf[key] = n; Sf[key] = s;
  }
  __syncthreads();

  if (t < 2) {
    float s = 0.0f;
    if (t == 0) {
      for (int b = 0; b < 256; ++b) {
        unsigned hb = Nf[2 * b] + (b ? Nf[2 * b - 1] : 0u);
        s += (float)hb;
      }
      s = fmaxf(s, 1.0f);
      float run = 0.0f;
      for (int b = 0; b < 256; ++b) {
        unsigned hb = Nf[2 * b] + (b ? Nf[2 * b - 1] : 0u);
        run += (float)hb / s;
        dcdf[b] = run;
      }
    } else {
      const unsigned* hh = gT;  // sum copies on the fly
      for (int b = 0; b < 256; ++b) {
        unsigned hb = 0;
#pragma unroll
        for (int cp = 0; cp < 4; ++cp) hb += hh[cp * 3072 + rc * 256 + b];
        s += (float)hb;
      }
      s = fmaxf(s, 1.0f);
      float run = 0.0f;
      for (int b = 0; b < 256; ++b) {
        unsigned hb = 0;
#pragma unroll
        for (int cp = 0; cp < 4; ++cp) hb += hh[cp * 3072 + rc * 256 + b];
        run += (float)hb / s;
        acdf[b] = run;
      }
    }
  }
  __syncthreads();

  int tb;
  if (t == 0) tb = 0;
  else if (t == 255) tb = 255;
  else {
    float di = dcdf[t];
    tb = t;
    for (int j = 1; j < 256; ++j) {
      if (di >= acdf[j - 1] && di <= acdf[j]) { tb = j; break; }
    }
  }

  // exact loss contribution for coarse bin b = t
  unsigned Nb = Nf[2 * t] + Nf[2 * t + 1];
  u64 Sb = Sf[2 * t] + Sf[2 * t + 1];
  s64 nt = (s64)Nb * ((s64)tb << 23);
  s64 contrib = (tb <= t) ? ((s64)Sb - nt) : (nt - (s64)Sb);
  red[t] = contrib;
  __syncthreads();
  for (int off = 128; off > 0; off >>= 1) {
    if (t < off) red[t] += red[t + off];
    __syncthreads();
  }
  if (t == 0) atomicAdd(acc, (u64)red[0]);
}

__global__ void finalize_kernel(const u64* __restrict__ acc,
                                float* __restrict__ out, int npix) {
  s64 total = (s64)acc[0];
  out[0] = (float)(0.1 * (double)total / 8388608.0 / (3.0 * (double)npix));
}

extern "C" void kernel_launch(void* const* d_in, const int* in_sizes, int n_in,
                              void* d_out, int out_size, void* d_ws, size_t ws_size,
                              hipStream_t stream) {
  const float* fake = (const float*)d_in[0];
  const float* refb = (const float*)d_in[1];
  const int* ma = (const int*)d_in[2];
  const int* mb = (const int*)d_in[3];
  const int npix = in_sizes[2];  // H*W

  unsigned* gN = (unsigned*)d_ws;                       // [4][6144] u32
  u64* gS = (u64*)((char*)d_ws + 98304);                // [4][6144] u64
  unsigned* gT = (unsigned*)((char*)d_ws + 294912);     // [4][3072] u32
  u64* acc = (u64*)((char*)d_ws + 344064);              // s64
  float* out = (float*)d_out;

  hipMemsetAsync(d_ws, 0, 344072, stream);
  // 60 KB LDS/block -> 2 blocks/CU; 512 blocks = 2 per CU (full occupancy).
  hist_kernel<<<512, 1024, 0, stream>>>(fake, refb, ma, mb, gN, gS, gT, npix);
  cdf_loss_kernel<<<12, 256, 0, stream>>>(gN, gS, gT, acc);
  finalize_kernel<<<1, 1, 0, stream>>>(acc, out, npix);
}

// Round 4
// 96.467 us; speedup vs baseline: 1.3405x; 1.3405x over previous
//
#include <hip/hip_runtime.h>

// HMLoss: 4-region histogram-matching L1 loss, H=W=2048.
// One image pass builds, per (src-region, channel), a 512-entry fine histogram
// keyed by key = 2*trunc(v) + (cdfbin(v) - trunc(v)), with packed (N<<48 | S)
// where S = sum of v in exact 2^23 fixed point. Loss is then computed from
// (N_b, S_b) per coarse bin without re-reading the image:
//   |v - t| summed over bin b = (t<=b) ? S_b - N_b*t : N_b*t - S_b   (exact).
//
// ws layout (4 flush copies to spread global-atomic contention):
//   [0, 98304)        u32 gN[4][6144]   src fine-bin counts
//   [98304, 294912)   u64 gS[4][6144]   src fine-bin sums (2^23 fixed point)
//   [294912, 344064)  u32 gT[4][3072]   tar cdf histograms
//   [344064, 344072)  s64 acc           loss accumulator (2^23 fixed point)

#define FACEA_BITS ((1u<<1)|(1u<<7)|(1u<<8)|(1u<<10)|(1u<<11)|(1u<<14))
#define FACEB_BITS ((1u<<1)|(1u<<7)|(1u<<8)|(1u<<10)|(1u<<14))
#define HAIR_BITS  (1u<<17)
#define EYEL_BITS  ((1u<<2)|(1u<<4))
#define EYER_BITS  ((1u<<3)|(1u<<5))

typedef unsigned long long u64;
typedef long long s64;

__device__ __forceinline__ float denorm255(float x) {
  float t = (x + 1.0f) * 0.5f;
  t = fminf(fmaxf(t, 0.0f), 1.0f);
  return t * 255.0f;
}

__device__ __forceinline__ int bin_of(float v) {
  int b = (int)floorf(v * (256.0f / 255.0f));
  b = b < 0 ? 0 : b;
  return b > 255 ? 255 : b;
}

__device__ __forceinline__ int regionA(unsigned bit) {
  if (bit & FACEA_BITS) return 0;
  if (bit & HAIR_BITS)  return 1;
  if (bit & EYEL_BITS)  return 2;
  if (bit & EYER_BITS)  return 3;
  return -1;
}
__device__ __forceinline__ int regionB(unsigned bit) {
  if (bit & FACEB_BITS) return 0;
  if (bit & HAIR_BITS)  return 1;
  if (bit & EYEL_BITS)  return 2;
  if (bit & EYER_BITS)  return 3;
  return -1;
}

__global__ __launch_bounds__(1024) void hist_kernel(
    const float* __restrict__ fake, const float* __restrict__ refb,
    const int* __restrict__ ma, const int* __restrict__ mb,
    unsigned* __restrict__ gN, u64* __restrict__ gS,
    unsigned* __restrict__ gT, int npix) {
  __shared__ u64 ns[6144];       // [region][chan][512] packed N<<48 | S
  __shared__ unsigned th[3072];  // tar cdf hist [region][chan][256]
  for (int i = threadIdx.x; i < 6144; i += blockDim.x) ns[i] = 0ull;
  for (int i = threadIdx.x; i < 3072; i += blockDim.x) th[i] = 0u;
  __syncthreads();

  const int nq = npix >> 2;
  const int stride = gridDim.x * blockDim.x;
  const float4* f0p = (const float4*)fake;
  const float4* f1p = (const float4*)(fake + npix);
  const float4* f2p = (const float4*)(fake + 2 * npix);
  const float4* r0p = (const float4*)refb;
  const float4* r1p = (const float4*)(refb + npix);
  const float4* r2p = (const float4*)(refb + 2 * npix);
  const int4* map = (const int4*)ma;
  const int4* mbp = (const int4*)mb;

  for (int q = blockIdx.x * blockDim.x + threadIdx.x; q < nq; q += stride) {
    int4 m4 = map[q];
    int4 b4 = mbp[q];
    float4 f0 = f0p[q], f1 = f1p[q], f2 = f2p[q];
    float4 r0 = r0p[q], r1 = r1p[q], r2 = r2p[q];
    int mm[4] = {m4.x, m4.y, m4.z, m4.w};
    int bb[4] = {b4.x, b4.y, b4.z, b4.w};
    float fa[3][4] = {{f0.x,f0.y,f0.z,f0.w},{f1.x,f1.y,f1.z,f1.w},{f2.x,f2.y,f2.z,f2.w}};
    float rr[3][4] = {{r0.x,r0.y,r0.z,r0.w},{r1.x,r1.y,r1.z,r1.w},{r2.x,r2.y,r2.z,r2.w}};
#pragma unroll
    for (int k = 0; k < 4; ++k) {
      int sreg = regionA(1u << (mm[k] & 31));
      if (sreg >= 0) {
#pragma unroll
        for (int c = 0; c < 3; ++c) {
          float v = denorm255(fa[c][k]);
          int c1 = (int)v;                    // trunc == floor, v >= 0
          int c2 = bin_of(v);
          int key = sreg * 1536 + c * 512 + 2 * c1 + (c2 - c1);
          u64 pack = (1ull << 48) | (u64)(v * 8388608.0f);  // exact enough (<=2^-23/entry)
          atomicAdd(&ns[key], pack);
        }
      }
      int treg = regionB(1u << (bb[k] & 31));
      int fval = (treg == 0 ? 1 : 0) + ((mm[k] == 11) ? 1 : 0);
      if (fval > 0) {
        float fs = (float)fval;
#pragma unroll
        for (int c = 0; c < 3; ++c)
          atomicAdd(&th[c * 256 + bin_of(denorm255(rr[c][k]) * fs)], 1u);
      }
      if (treg >= 1) {
#pragma unroll
        for (int c = 0; c < 3; ++c)
          atomicAdd(&th[treg * 768 + c * 256 + bin_of(denorm255(rr[c][k]))], 1u);
      }
    }
  }
  __syncthreads();

  // flush to one of 4 global copies, rotated start to spread contention.
  // NOTE: 6144/3072 are NOT powers of two -> conditional wrap, never & mask.
  int copy = blockIdx.x & 3;
  int rot = (blockIdx.x >> 2) & 63;
  for (int i = threadIdx.x; i < 6144; i += blockDim.x) {
    int j = i + rot * 96; if (j >= 6144) j -= 6144;
    u64 v = ns[j];
    if (v) {
      atomicAdd(&gN[copy * 6144 + j], (unsigned)(v >> 48));
      atomicAdd(&gS[copy * 6144 + j], v & 0xFFFFFFFFFFFFull);
    }
  }
  for (int i = threadIdx.x; i < 3072; i += blockDim.x) {
    int j = i + rot * 48; if (j >= 3072) j -= 3072;
    unsigned v = th[j];
    if (v) atomicAdd(&gT[copy * 3072 + j], v);
  }
}

// 12 blocks, one per (region, channel). ALL global data staged to LDS in
// parallel first; totals by exact parallel tree reduce (integer partial sums
// < 2^22 are f32-exact in any order); the two bit-faithful serial cumsums
// run LDS-only on DIFFERENT waves (t==0, t==64) so they overlap.
__global__ __launch_bounds__(256) void cdf_loss_kernel(
    const unsigned* __restrict__ gN, const u64* __restrict__ gS,
    const unsigned* __restrict__ gT, u64* __restrict__ acc) {
  __shared__ unsigned Nf[512];
  __shared__ u64 Sf[512];
  __shared__ unsigned thA[256];
  __shared__ float hbD[256];
  __shared__ float dcdf[256];
  __shared__ float acdf[256];
  __shared__ unsigned rsum[512];   // [0..255] dst total, [256..511] tar total
  __shared__ s64 red[256];
  int rc = blockIdx.x;             // 0..11
  int base = (rc / 3) * 1536 + (rc % 3) * 512;
  int t = threadIdx.x;

  // parallel stage: sum the 4 flush copies of everything
  {
    unsigned n0 = 0, n1 = 0, ta = 0; u64 s0 = 0, s1 = 0;
#pragma unroll
    for (int cp = 0; cp < 4; ++cp) {
      n0 += gN[cp * 6144 + base + 2 * t];
      n1 += gN[cp * 6144 + base + 2 * t + 1];
      s0 += gS[cp * 6144 + base + 2 * t];
      s1 += gS[cp * 6144 + base + 2 * t + 1];
      ta += gT[cp * 3072 + rc * 256 + t];
    }
    Nf[2 * t] = n0; Nf[2 * t + 1] = n1;
    Sf[2 * t] = s0; Sf[2 * t + 1] = s1;
    thA[t] = ta;
  }
  __syncthreads();

  // dst-CDF histogram bin t gathers fine keys 2t and 2t-1
  unsigned hD = Nf[2 * t] + (t ? Nf[2 * t - 1] : 0u);
  hbD[t] = (float)hD;
  rsum[t] = hD;
  rsum[256 + t] = thA[t];
  __syncthreads();
  for (int off = 128; off > 0; off >>= 1) {
    if (t < off) { rsum[t] += rsum[t + off]; rsum[256 + t] += rsum[256 + t + off]; }
    __syncthreads();
  }

  if (t == 0) {            // wave 0: dst cumsum (serial, LDS-only)
    float s = fmaxf((float)rsum[0], 1.0f);
    float run = 0.0f;
    for (int b = 0; b < 256; ++b) { run += hbD[b] / s; dcdf[b] = run; }
  }
  if (t == 64) {           // wave 1: tar cumsum, concurrent with wave 0
    float s = fmaxf((float)rsum[256], 1.0f);
    float run = 0.0f;
    for (int b = 0; b < 256; ++b) { run += (float)thA[b] / s; acdf[b] = run; }
  }
  __syncthreads();

  int tb;
  if (t == 0) tb = 0;
  else if (t == 255) tb = 255;
  else {
    float di = dcdf[t];
    tb = t;
    for (int j = 1; j < 256; ++j) {
      if (di >= acdf[j - 1] && di <= acdf[j]) { tb = j; break; }
    }
  }

  // exact loss contribution for coarse bin b = t
  unsigned Nb = Nf[2 * t] + Nf[2 * t + 1];
  u64 Sb = Sf[2 * t] + Sf[2 * t + 1];
  s64 nt = (s64)Nb * ((s64)tb << 23);
  s64 contrib = (tb <= t) ? ((s64)Sb - nt) : (nt - (s64)Sb);
  red[t] = contrib;
  __syncthreads();
  for (int off = 128; off > 0; off >>= 1) {
    if (t < off) red[t] += red[t + off];
    __syncthreads();
  }
  if (t == 0) atomicAdd(acc, (u64)red[0]);
}

__global__ void finalize_kernel(const u64* __restrict__ acc,
                                float* __restrict__ out, int npix) {
  s64 total = (s64)acc[0];
  out[0] = (float)(0.1 * (double)total / 8388608.0 / (3.0 * (double)npix));
}

extern "C" void kernel_launch(void* const* d_in, const int* in_sizes, int n_in,
                              void* d_out, int out_size, void* d_ws, size_t ws_size,
                              hipStream_t stream) {
  const float* fake = (const float*)d_in[0];
  const float* refb = (const float*)d_in[1];
  const int* ma = (const int*)d_in[2];
  const int* mb = (const int*)d_in[3];
  const int npix = in_sizes[2];  // H*W

  unsigned* gN = (unsigned*)d_ws;                       // [4][6144] u32
  u64* gS = (u64*)((char*)d_ws + 98304);                // [4][6144] u64
  unsigned* gT = (unsigned*)((char*)d_ws + 294912);     // [4][3072] u32
  u64* acc = (u64*)((char*)d_ws + 344064);              // s64
  float* out = (float*)d_out;

  hipMemsetAsync(d_ws, 0, 344072, stream);
  // 60 KB LDS/block -> 2 blocks/CU; 512 blocks = 2 per CU (full occupancy).
  hist_kernel<<<512, 1024, 0, stream>>>(fake, refb, ma, mb, gN, gS, gT, npix);
  cdf_loss_kernel<<<12, 256, 0, stream>>>(gN, gS, gT, acc);
  finalize_kernel<<<1, 1, 0, stream>>>(acc, out, npix);
}

// Round 5
// 91.622 us; speedup vs baseline: 1.4114x; 1.0529x over previous
//
#include <hip/hip_runtime.h>

// HMLoss: 4-region histogram-matching L1 loss, H=W=2048.
// One image pass builds, per (src-region, channel), a 512-entry fine histogram
// keyed by key = trunc(v) + cdfbin(v), with packed (N<<41 | S) where
// S = sum of v in exact 2^11 fixed point (v*2048 is exact: pow2 scale).
// Loss from per-coarse-bin stats: sum|v-t| = (t<=b) ? S-N*t : N*t-S.
// Extreme values (bin 0 / bin 255 pile-ups from the clamp: ~16% of pixels
// each) go to 8 per-lane alias slots, merged in LDS before flush.
//
// ws layout (8 flush copies):
//   [0, 393216)        u64 gNS[8][12][512]  src packed stats
//   [393216, 491520)   u64 gT [8][12][128]  tar hist, bins packed in pairs
//   [491520, 491528)   s64 acc              loss accumulator (2^11 fixed pt)

#define FACEA_BITS ((1u<<1)|(1u<<7)|(1u<<8)|(1u<<10)|(1u<<11)|(1u<<14))
#define FACEB_BITS ((1u<<1)|(1u<<7)|(1u<<8)|(1u<<10)|(1u<<14))
#define HAIR_BITS  (1u<<17)
#define EYEL_BITS  ((1u<<2)|(1u<<4))
#define EYER_BITS  ((1u<<3)|(1u<<5))

typedef unsigned long long u64;
typedef long long s64;

#define NSTRIDE 528   // 512 fine keys + 8 zero-aliases + 8 max-aliases
#define TSTRIDE 272   // 256 bins + 8 + 8
#define M41 ((1ull << 41) - 1)

__device__ __forceinline__ float denorm255(float x) {
  float t = (x + 1.0f) * 0.5f;
  t = fminf(fmaxf(t, 0.0f), 1.0f);
  return t * 255.0f;
}

__device__ __forceinline__ int bin_of(float v) {
  int b = (int)floorf(v * (256.0f / 255.0f));
  b = b < 0 ? 0 : b;
  return b > 255 ? 255 : b;
}

__device__ __forceinline__ int regionA(unsigned bit) {
  if (bit & FACEA_BITS) return 0;
  if (bit & HAIR_BITS)  return 1;
  if (bit & EYEL_BITS)  return 2;
  if (bit & EYER_BITS)  return 3;
  return -1;
}
__device__ __forceinline__ int regionB(unsigned bit) {
  if (bit & FACEB_BITS) return 0;
  if (bit & HAIR_BITS)  return 1;
  if (bit & EYEL_BITS)  return 2;
  if (bit & EYER_BITS)  return 3;
  return -1;
}

__global__ __launch_bounds__(1024) void hist_kernel(
    const float* __restrict__ fake, const float* __restrict__ refb,
    const int* __restrict__ ma, const int* __restrict__ mb,
    u64* __restrict__ gNS, u64* __restrict__ gT, int npix) {
  __shared__ u64 ns[12 * NSTRIDE];       // packed N<<41 | S(2^11 fixed)
  __shared__ unsigned th[12 * TSTRIDE];  // tar cdf hist
  for (int i = threadIdx.x; i < 12 * NSTRIDE; i += blockDim.x) ns[i] = 0ull;
  for (int i = threadIdx.x; i < 12 * TSTRIDE; i += blockDim.x) th[i] = 0u;
  __syncthreads();

  const int lane8 = threadIdx.x & 7;
  const int nq = npix >> 2;
  const int stride = gridDim.x * blockDim.x;
  const float4* f0p = (const float4*)fake;
  const float4* f1p = (const float4*)(fake + npix);
  const float4* f2p = (const float4*)(fake + 2 * npix);
  const float4* r0p = (const float4*)refb;
  const float4* r1p = (const float4*)(refb + npix);
  const float4* r2p = (const float4*)(refb + 2 * npix);
  const int4* map = (const int4*)ma;
  const int4* mbp = (const int4*)mb;

  for (int q = blockIdx.x * blockDim.x + threadIdx.x; q < nq; q += stride) {
    int4 m4 = map[q];
    int4 b4 = mbp[q];
    float4 f0 = f0p[q], f1 = f1p[q], f2 = f2p[q];
    float4 r0 = r0p[q], r1 = r1p[q], r2 = r2p[q];
    int mm[4] = {m4.x, m4.y, m4.z, m4.w};
    int bb[4] = {b4.x, b4.y, b4.z, b4.w};
    float fa[3][4] = {{f0.x,f0.y,f0.z,f0.w},{f1.x,f1.y,f1.z,f1.w},{f2.x,f2.y,f2.z,f2.w}};
    float rr[3][4] = {{r0.x,r0.y,r0.z,r0.w},{r1.x,r1.y,r1.z,r1.w},{r2.x,r2.y,r2.z,r2.w}};
#pragma unroll
    for (int k = 0; k < 4; ++k) {
      int sreg = regionA(1u << (mm[k] & 31));
      if (sreg >= 0) {
#pragma unroll
        for (int c = 0; c < 3; ++c) {
          float v = denorm255(fa[c][k]);
          int c1 = (int)v;                    // trunc == floor, v >= 0
          int c2 = bin_of(v);
          int key = c1 + c2;                  // == 2*c1 + (c2-c1)
          if (v == 0.0f) key = 512 + lane8;        // clamp pile-up -> aliases
          else if (v == 255.0f) key = 520 + lane8;
          u64 pack = (1ull << 41) | (u64)(v * 2048.0f);  // exact mul (pow2)
          atomicAdd(&ns[(sreg * 3 + c) * NSTRIDE + key], pack);
        }
      }
      int treg = regionB(1u << (bb[k] & 31));
      int fval = (treg == 0 ? 1 : 0) + ((mm[k] == 11) ? 1 : 0);
      if (fval > 0) {
        float fs = (float)fval;
#pragma unroll
        for (int c = 0; c < 3; ++c) {
          int bt = bin_of(denorm255(rr[c][k]) * fs);
          int idx = bt;
          if (bt == 0) idx = 256 + lane8;
          else if (bt == 255) idx = 264 + lane8;
          atomicAdd(&th[c * TSTRIDE + idx], 1u);
        }
      }
      if (treg >= 1) {
#pragma unroll
        for (int c = 0; c < 3; ++c) {
          int bt = bin_of(denorm255(rr[c][k]));
          int idx = bt;
          if (bt == 0) idx = 256 + lane8;
          else if (bt == 255) idx = 264 + lane8;
          atomicAdd(&th[(treg * 3 + c) * TSTRIDE + idx], 1u);
        }
      }
    }
  }
  __syncthreads();

  // merge aliases back into base bins (v==0 -> fine key 0; v==255 -> key 510)
  if (threadIdx.x < 24) {
    int rc = threadIdx.x >> 1, hi = threadIdx.x & 1;
    u64* base = &ns[rc * NSTRIDE];
    u64 s = 0;
    int a0 = 512 + hi * 8;
#pragma unroll
    for (int j = 0; j < 8; ++j) s += base[a0 + j];
    base[hi ? 510 : 0] += s;
  } else if (threadIdx.x >= 64 && threadIdx.x < 88) {
    int q2 = threadIdx.x - 64;
    int rc = q2 >> 1, hi = q2 & 1;
    unsigned* base = &th[rc * TSTRIDE];
    unsigned s = 0;
    int a0 = 256 + hi * 8;
#pragma unroll
    for (int j = 0; j < 8; ++j) s += base[a0 + j];
    base[hi ? 255 : 0] += s;
  }
  __syncthreads();

  // flush: one u64 atomic per nonzero entry, 8 copies, rotated start
  int copy = blockIdx.x & 7;
  int rot8 = ((blockIdx.x >> 3) & 63) * 8;
  for (int i = threadIdx.x; i < 6144; i += blockDim.x) {
    int rc = i >> 9;
    int key = ((i & 511) + rot8) & 511;
    u64 v = ns[rc * NSTRIDE + key];
    if (v) atomicAdd(&gNS[copy * 6144 + rc * 512 + key], v);
  }
  for (int i = threadIdx.x; i < 1536; i += blockDim.x) {
    int rc = i >> 7;
    int p = ((i & 127) + rot8) & 127;
    unsigned lo = th[rc * TSTRIDE + 2 * p];
    unsigned hi2 = th[rc * TSTRIDE + 2 * p + 1];
    u64 w = (u64)lo | ((u64)hi2 << 32);
    if (w) atomicAdd(&gT[copy * 1536 + rc * 128 + p], w);
  }
}

// 12 blocks, one per (region, channel). All staging parallel; exact integer
// tree totals; the two bit-faithful serial cumsums run LDS-only on different
// waves so they overlap.
__global__ __launch_bounds__(256) void cdf_loss_kernel(
    const u64* __restrict__ gNS, const u64* __restrict__ gT,
    u64* __restrict__ acc) {
  __shared__ unsigned Nf[512];
  __shared__ u64 Sf[512];
  __shared__ unsigned thA[256];
  __shared__ float hbD[256];
  __shared__ float dcdf[256];
  __shared__ float acdf[256];
  __shared__ unsigned rsum[512];   // [0..255] dst total, [256..511] tar total
  __shared__ s64 red[256];
  int rc = blockIdx.x;             // 0..11
  int t = threadIdx.x;

  {
    u64 a0 = 0, a1 = 0, w = 0;
#pragma unroll
    for (int cp = 0; cp < 8; ++cp) {
      a0 += gNS[cp * 6144 + rc * 512 + 2 * t];
      a1 += gNS[cp * 6144 + rc * 512 + 2 * t + 1];
      if (t < 128) w += gT[cp * 1536 + rc * 128 + t];
    }
    Nf[2 * t] = (unsigned)(a0 >> 41); Sf[2 * t] = a0 & M41;
    Nf[2 * t + 1] = (unsigned)(a1 >> 41); Sf[2 * t + 1] = a1 & M41;
    if (t < 128) {
      thA[2 * t] = (unsigned)(w & 0xFFFFFFFFull);
      thA[2 * t + 1] = (unsigned)(w >> 32);
    }
  }
  __syncthreads();

  // dst-CDF histogram bin t gathers fine keys 2t and 2t-1
  unsigned hD = Nf[2 * t] + (t ? Nf[2 * t - 1] : 0u);
  hbD[t] = (float)hD;
  rsum[t] = hD;
  rsum[256 + t] = thA[t];
  __syncthreads();
  for (int off = 128; off > 0; off >>= 1) {
    if (t < off) { rsum[t] += rsum[t + off]; rsum[256 + t] += rsum[256 + t + off]; }
    __syncthreads();
  }

  if (t == 0) {            // wave 0: dst cumsum (serial, LDS-only)
    float s = fmaxf((float)rsum[0], 1.0f);
    float run = 0.0f;
    for (int b = 0; b < 256; ++b) { run += hbD[b] / s; dcdf[b] = run; }
  }
  if (t == 64) {           // wave 1: tar cumsum, concurrent with wave 0
    float s = fmaxf((float)rsum[256], 1.0f);
    float run = 0.0f;
    for (int b = 0; b < 256; ++b) { run += (float)thA[b] / s; acdf[b] = run; }
  }
  __syncthreads();

  int tb;
  if (t == 0) tb = 0;
  else if (t == 255) tb = 255;
  else {
    float di = dcdf[t];
    tb = t;
    for (int j = 1; j < 256; ++j) {
      if (di >= acdf[j - 1] && di <= acdf[j]) { tb = j; break; }
    }
  }

  // exact loss contribution for coarse bin b = t (2^11 fixed point)
  unsigned Nb = Nf[2 * t] + Nf[2 * t + 1];
  u64 Sb = Sf[2 * t] + Sf[2 * t + 1];
  s64 nt = (s64)Nb * ((s64)tb << 11);
  s64 contrib = (tb <= t) ? ((s64)Sb - nt) : (nt - (s64)Sb);
  red[t] = contrib;
  __syncthreads();
  for (int off = 128; off > 0; off >>= 1) {
    if (t < off) red[t] += red[t + off];
    __syncthreads();
  }
  if (t == 0) atomicAdd(acc, (u64)red[0]);
}

__global__ void finalize_kernel(const u64* __restrict__ acc,
                                float* __restrict__ out, int npix) {
  s64 total = (s64)acc[0];
  out[0] = (float)(0.1 * (double)total / 2048.0 / (3.0 * (double)npix));
}

extern "C" void kernel_launch(void* const* d_in, const int* in_sizes, int n_in,
                              void* d_out, int out_size, void* d_ws, size_t ws_size,
                              hipStream_t stream) {
  const float* fake = (const float*)d_in[0];
  const float* refb = (const float*)d_in[1];
  const int* ma = (const int*)d_in[2];
  const int* mb = (const int*)d_in[3];
  const int npix = in_sizes[2];  // H*W

  u64* gNS = (u64*)d_ws;                                // [8][12][512] u64
  u64* gT = (u64*)((char*)d_ws + 393216);               // [8][12][128] u64
  u64* acc = (u64*)((char*)d_ws + 491520);              // s64
  float* out = (float*)d_out;

  hipMemsetAsync(d_ws, 0, 491528, stream);
  // 63.7 KB LDS/block -> 2 blocks/CU; 512 blocks = 2 per CU.
  hist_kernel<<<512, 1024, 0, stream>>>(fake, refb, ma, mb, gNS, gT, npix);
  cdf_loss_kernel<<<12, 256, 0, stream>>>(gNS, gT, acc);
  finalize_kernel<<<1, 1, 0, stream>>>(acc, out, npix);
}

// Round 6
// 88.202 us; speedup vs baseline: 1.4661x; 1.0388x over previous
//
#include <hip/hip_runtime.h>

// HMLoss: 4-region histogram-matching L1 loss, H=W=2048.
// Single image pass, block-specialized: blocks [0,256) build the src fine
// histogram (fake+mask_A), blocks [256,512) build the tar cdf histogram
// (ref_B+mask_B+mask_A for the ==11 bug term). Src fine hist is keyed by
// key = trunc(v) + cdfbin(v) with packed (N<<41 | S), S = v in exact 2^11
// fixed point. Loss from per-coarse-bin stats:
//   sum|v-t| over bin b = (t<=b) ? S-N*t : N*t-S   (exact integer).
// Extreme values (clamp pile-ups at v=0/255, ~16% each) use 8 per-lane alias
// slots merged before flush.
//
// ws layout (8 flush copies):
//   [0, 393216)        u64 gNS[8][12][512]  src packed stats
//   [393216, 491520)   u64 gT [8][12][128]  tar hist, bins packed in pairs
//   [491520, 491528)   s64 acc              loss accumulator (2^11 fixed pt)

#define FACEA_BITS ((1u<<1)|(1u<<7)|(1u<<8)|(1u<<10)|(1u<<11)|(1u<<14))
#define FACEB_BITS ((1u<<1)|(1u<<7)|(1u<<8)|(1u<<10)|(1u<<14))
#define HAIR_BITS  (1u<<17)
#define EYEL_BITS  ((1u<<2)|(1u<<4))
#define EYER_BITS  ((1u<<3)|(1u<<5))

typedef unsigned long long u64;
typedef long long s64;

#define NSTRIDE 528   // 512 fine keys + 8 zero-aliases + 8 max-aliases
#define TSTRIDE 272   // 256 bins + 8 + 8
#define M41 ((1ull << 41) - 1)
#define NSRC 256      // src blocks; tar blocks = [NSRC, 512)

__device__ __forceinline__ float denorm255(float x) {
  float t = (x + 1.0f) * 0.5f;
  t = fminf(fmaxf(t, 0.0f), 1.0f);
  return t * 255.0f;
}

// v >= 0 guaranteed: cast = trunc = floor; only upper clamp needed.
__device__ __forceinline__ int bin_of(float v) {
  int b = (int)(v * (256.0f / 255.0f));
  return b > 255 ? 255 : b;
}

__device__ __forceinline__ int regionA(unsigned bit) {
  if (bit & FACEA_BITS) return 0;
  if (bit & HAIR_BITS)  return 1;
  if (bit & EYEL_BITS)  return 2;
  if (bit & EYER_BITS)  return 3;
  return -1;
}
__device__ __forceinline__ int regionB(unsigned bit) {
  if (bit & FACEB_BITS) return 0;
  if (bit & HAIR_BITS)  return 1;
  if (bit & EYEL_BITS)  return 2;
  if (bit & EYER_BITS)  return 3;
  return -1;
}

__global__ __launch_bounds__(1024) void hist_kernel(
    const float* __restrict__ fake, const float* __restrict__ refb,
    const int* __restrict__ ma, const int* __restrict__ mb,
    u64* __restrict__ gNS, u64* __restrict__ gT, int npix) {
  __shared__ u64 ns[12 * NSTRIDE];       // src: packed N<<41 | S(2^11 fixed)
  __shared__ unsigned th[12 * TSTRIDE];  // tar cdf hist
  const int lane8 = threadIdx.x & 7;
  const int nq = npix >> 2;
  const bool is_src = blockIdx.x < NSRC;

  if (is_src) {
    for (int i = threadIdx.x; i < 12 * NSTRIDE; i += blockDim.x) ns[i] = 0ull;
    __syncthreads();

    const int stride = NSRC * blockDim.x;
    const float4* f0p = (const float4*)fake;
    const float4* f1p = (const float4*)(fake + npix);
    const float4* f2p = (const float4*)(fake + 2 * npix);
    const int4* map = (const int4*)ma;

    int q = blockIdx.x * blockDim.x + threadIdx.x;
    int4 mc; float4 c0, c1v, c2v;
    if (q < nq) { mc = map[q]; c0 = f0p[q]; c1v = f1p[q]; c2v = f2p[q]; }
    while (q < nq) {
      int qn = q + stride;
      int4 mn; float4 n0, n1, n2;
      if (qn < nq) { mn = map[qn]; n0 = f0p[qn]; n1 = f1p[qn]; n2 = f2p[qn]; }
      int mm[4] = {mc.x, mc.y, mc.z, mc.w};
      float fa[3][4] = {{c0.x,c0.y,c0.z,c0.w},{c1v.x,c1v.y,c1v.z,c1v.w},
                        {c2v.x,c2v.y,c2v.z,c2v.w}};
#pragma unroll
      for (int k = 0; k < 4; ++k) {
        int sreg = regionA(1u << (mm[k] & 31));
        if (sreg >= 0) {
#pragma unroll
          for (int c = 0; c < 3; ++c) {
            float v = denorm255(fa[c][k]);
            int key = (int)v + bin_of(v);       // 2*c1 + (c2-c1)
            if (v == 0.0f) key = 512 + lane8;   // clamp pile-up aliases
            else if (v == 255.0f) key = 520 + lane8;
            u64 pack = (1ull << 41) | (u64)(unsigned)(v * 2048.0f);
            atomicAdd(&ns[(sreg * 3 + c) * NSTRIDE + key], pack);
          }
        }
      }
      q = qn; mc = mn; c0 = n0; c1v = n1; c2v = n2;
    }
    __syncthreads();

    // merge aliases (v==0 -> fine key 0; v==255 -> key 510)
    if (threadIdx.x < 24) {
      int rc = threadIdx.x >> 1, hi = threadIdx.x & 1;
      u64* base = &ns[rc * NSTRIDE];
      u64 s = 0;
      int a0 = 512 + hi * 8;
#pragma unroll
      for (int j = 0; j < 8; ++j) s += base[a0 + j];
      base[hi ? 510 : 0] += s;
    }
    __syncthreads();

    // flush ns: 8 copies, rotated start
    int copy = blockIdx.x & 7;
    int rot8 = ((blockIdx.x >> 3) & 63) * 8;
    for (int i = threadIdx.x; i < 6144; i += blockDim.x) {
      int rc = i >> 9;
      int key = ((i & 511) + rot8) & 511;
      u64 v = ns[rc * NSTRIDE + key];
      if (v) atomicAdd(&gNS[copy * 6144 + rc * 512 + key], v);
    }
  } else {
    for (int i = threadIdx.x; i < 12 * TSTRIDE; i += blockDim.x) th[i] = 0u;
    __syncthreads();

    const int nb = 512 - NSRC;
    const int stride = nb * blockDim.x;
    const float4* r0p = (const float4*)refb;
    const float4* r1p = (const float4*)(refb + npix);
    const float4* r2p = (const float4*)(refb + 2 * npix);
    const int4* map = (const int4*)ma;
    const int4* mbp = (const int4*)mb;

    int q = (blockIdx.x - NSRC) * blockDim.x + threadIdx.x;
    int4 mac, mbc; float4 c0, c1v, c2v;
    if (q < nq) { mac = map[q]; mbc = mbp[q]; c0 = r0p[q]; c1v = r1p[q]; c2v = r2p[q]; }
    while (q < nq) {
      int qn = q + stride;
      int4 man, mbn; float4 n0, n1, n2;
      if (qn < nq) { man = map[qn]; mbn = mbp[qn]; n0 = r0p[qn]; n1 = r1p[qn]; n2 = r2p[qn]; }
      int mm[4] = {mac.x, mac.y, mac.z, mac.w};
      int bb[4] = {mbc.x, mbc.y, mbc.z, mbc.w};
      float rr[3][4] = {{c0.x,c0.y,c0.z,c0.w},{c1v.x,c1v.y,c1v.z,c1v.w},
                        {c2v.x,c2v.y,c2v.z,c2v.w}};
#pragma unroll
      for (int k = 0; k < 4; ++k) {
        int treg = regionB(1u << (bb[k] & 31));
        int fval = (treg == 0 ? 1 : 0) + ((mm[k] == 11) ? 1 : 0);
        if (fval > 0) {
          float fs = (float)fval;
#pragma unroll
          for (int c = 0; c < 3; ++c) {
            int bt = bin_of(denorm255(rr[c][k]) * fs);
            int idx = bt;
            if (bt == 0) idx = 256 + lane8;
            else if (bt == 255) idx = 264 + lane8;
            atomicAdd(&th[c * TSTRIDE + idx], 1u);
          }
        }
        if (treg >= 1) {
#pragma unroll
          for (int c = 0; c < 3; ++c) {
            int bt = bin_of(denorm255(rr[c][k]));
            int idx = bt;
            if (bt == 0) idx = 256 + lane8;
            else if (bt == 255) idx = 264 + lane8;
            atomicAdd(&th[(treg * 3 + c) * TSTRIDE + idx], 1u);
          }
        }
      }
      q = qn; mac = man; mbc = mbn; c0 = n0; c1v = n1; c2v = n2;
    }
    __syncthreads();

    if (threadIdx.x < 24) {
      int rc = threadIdx.x >> 1, hi = threadIdx.x & 1;
      unsigned* base = &th[rc * TSTRIDE];
      unsigned s = 0;
      int a0 = 256 + hi * 8;
#pragma unroll
      for (int j = 0; j < 8; ++j) s += base[a0 + j];
      base[hi ? 255 : 0] += s;
    }
    __syncthreads();

    // flush th as bin-pairs packed in u64 (no cross-carry: totals < 2^32)
    int copy = blockIdx.x & 7;
    int rot8 = ((blockIdx.x >> 3) & 63) * 8;
    for (int i = threadIdx.x; i < 1536; i += blockDim.x) {
      int rc = i >> 7;
      int p = ((i & 127) + rot8) & 127;
      unsigned lo = th[rc * TSTRIDE + 2 * p];
      unsigned hi2 = th[rc * TSTRIDE + 2 * p + 1];
      u64 w = (u64)lo | ((u64)hi2 << 32);
      if (w) atomicAdd(&gT[copy * 1536 + rc * 128 + p], w);
    }
  }
}

// 12 blocks, one per (region, channel). All staging parallel; exact integer
// tree totals; the two bit-faithful serial cumsums run LDS-only on different
// waves so they overlap.
__global__ __launch_bounds__(256) void cdf_loss_kernel(
    const u64* __restrict__ gNS, const u64* __restrict__ gT,
    u64* __restrict__ acc) {
  __shared__ unsigned Nf[512];
  __shared__ u64 Sf[512];
  __shared__ unsigned thA[256];
  __shared__ float hbD[256];
  __shared__ float dcdf[256];
  __shared__ float acdf[256];
  __shared__ unsigned rsum[512];   // [0..255] dst total, [256..511] tar total
  __shared__ s64 red[256];
  int rc = blockIdx.x;             // 0..11
  int t = threadIdx.x;

  {
    u64 a0 = 0, a1 = 0, w = 0;
#pragma unroll
    for (int cp = 0; cp < 8; ++cp) {
      a0 += gNS[cp * 6144 + rc * 512 + 2 * t];
      a1 += gNS[cp * 6144 + rc * 512 + 2 * t + 1];
      if (t < 128) w += gT[cp * 1536 + rc * 128 + t];
    }
    Nf[2 * t] = (unsigned)(a0 >> 41); Sf[2 * t] = a0 & M41;
    Nf[2 * t + 1] = (unsigned)(a1 >> 41); Sf[2 * t + 1] = a1 & M41;
    if (t < 128) {
      thA[2 * t] = (unsigned)(w & 0xFFFFFFFFull);
      thA[2 * t + 1] = (unsigned)(w >> 32);
    }
  }
  __syncthreads();

  // dst-CDF histogram bin t gathers fine keys 2t and 2t-1
  unsigned hD = Nf[2 * t] + (t ? Nf[2 * t - 1] : 0u);
  hbD[t] = (float)hD;
  rsum[t] = hD;
  rsum[256 + t] = thA[t];
  __syncthreads();
  for (int off = 128; off > 0; off >>= 1) {
    if (t < off) { rsum[t] += rsum[t + off]; rsum[256 + t] += rsum[256 + t + off]; }
    __syncthreads();
  }

  if (t == 0) {            // wave 0: dst cumsum (serial, LDS-only)
    float s = fmaxf((float)rsum[0], 1.0f);
    float run = 0.0f;
    for (int b = 0; b < 256; ++b) { run += hbD[b] / s; dcdf[b] = run; }
  }
  if (t == 64) {           // wave 1: tar cumsum, concurrent with wave 0
    float s = fmaxf((float)rsum[256], 1.0f);
    float run = 0.0f;
    for (int b = 0; b < 256; ++b) { run += (float)thA[b] / s; acdf[b] = run; }
  }
  __syncthreads();

  int tb;
  if (t == 0) tb = 0;
  else if (t == 255) tb = 255;
  else {
    float di = dcdf[t];
    tb = t;
    for (int j = 1; j < 256; ++j) {
      if (di >= acdf[j - 1] && di <= acdf[j]) { tb = j; break; }
    }
  }

  // exact loss contribution for coarse bin b = t (2^11 fixed point)
  unsigned Nb = Nf[2 * t] + Nf[2 * t + 1];
  u64 Sb = Sf[2 * t] + Sf[2 * t + 1];
  s64 nt = (s64)Nb * ((s64)tb << 11);
  s64 contrib = (tb <= t) ? ((s64)Sb - nt) : (nt - (s64)Sb);
  red[t] = contrib;
  __syncthreads();
  for (int off = 128; off > 0; off >>= 1) {
    if (t < off) red[t] += red[t + off];
    __syncthreads();
  }
  if (t == 0) atomicAdd(acc, (u64)red[0]);
}

__global__ void finalize_kernel(const u64* __restrict__ acc,
                                float* __restrict__ out, int npix) {
  s64 total = (s64)acc[0];
  out[0] = (float)(0.1 * (double)total / 2048.0 / (3.0 * (double)npix));
}

extern "C" void kernel_launch(void* const* d_in, const int* in_sizes, int n_in,
                              void* d_out, int out_size, void* d_ws, size_t ws_size,
                              hipStream_t stream) {
  const float* fake = (const float*)d_in[0];
  const float* refb = (const float*)d_in[1];
  const int* ma = (const int*)d_in[2];
  const int* mb = (const int*)d_in[3];
  const int npix = in_sizes[2];  // H*W

  u64* gNS = (u64*)d_ws;                                // [8][12][512] u64
  u64* gT = (u64*)((char*)d_ws + 393216);               // [8][12][128] u64
  u64* acc = (u64*)((char*)d_ws + 491520);              // s64
  float* out = (float*)d_out;

  hipMemsetAsync(d_ws, 0, 491528, stream);
  // 63.7 KB LDS/block -> 2 blocks/CU (one src + one tar block per CU).
  hist_kernel<<<512, 1024, 0, stream>>>(fake, refb, ma, mb, gNS, gT, npix);
  cdf_loss_kernel<<<12, 256, 0, stream>>>(gNS, gT, acc);
  finalize_kernel<<<1, 1, 0, stream>>>(acc, out, npix);
}